// Round 5
// baseline (429.323 us; speedup 1.0000x reference)
//
#include <hip/hip_runtime.h>

// SSIM loss v5 — streaming separable conv, 2 rows per step (fat steps).
// Grid 8 x 8 x 48 = 3072 blocks of 64 threads = 1 wave (no barriers).
// Wave strip: 64 cols x 64 output rows (74 input rows = 37 steps x 2 rows).
// Each lane owns ONE output column; per step:
//   1. window-read rows 2t,2t+1 from ping-pong buffer (staged last step):
//      11 interleaved {a,b} v2f pairs each, stride-2-word b64 = conflict-free.
//   2. stage rows 2t+2,2t+3 (fetched last step) into other buffer (clamped).
//   3. prefetch rows 2t+4,2t+5 from global into registers.
//   4. horizontal 11-tap conv x2 rows -> 12-slot register ring (slot = row%12,
//      static under 12-step chunks).
//   5. vertical 11-tap conv from ring + SSIM for output rows 2t-10, 2t-9.
// Fat steps (~230 VALU) amortize the fixed LDS/global latency chain; ring
// stays 60 floats regardless of rows/step. One atomicAdd per wave.

typedef float v2f __attribute__((ext_vector_type(2)));
typedef float v4f __attribute__((ext_vector_type(4)));

#define IMG    512
#define SROWS  64
#define NSTEPS 37
#define NPIX   (16.0f * 3.0f * 512.0f * 512.0f)

__device__ __forceinline__ float clamp01(float x) {
    // fmaxf(NaN,0) -> 0: nan_to_num + clip(0,1)
    return fminf(fmaxf(x, 0.0f), 1.0f);
}

__device__ __forceinline__ float ssim_px(v2f mu, v2f e, float e12) {
    const float C1 = 1.01e-4f;   // 0.01^2 + 1e-6
    const float C2 = 9.01e-4f;   // 0.03^2 + 1e-6
    v2f musq = mu * mu;
    float mu12 = mu.x * mu.y;
    v2f sig = e - musq;
    sig = __builtin_elementwise_max(sig, (v2f){1e-6f, 1e-6f});
    sig = __builtin_elementwise_min(sig, (v2f){1e6f, 1e6f});
    float s12 = e12 - mu12;
    float num = fmaf(2.f, mu12, C1) * fmaf(2.f, s12, C2);
    float den = (musq.x + musq.y + C1) * (sig.x + sig.y + C2);  // >= C1*C2 > 0
    return num * __builtin_amdgcn_rcpf(den);
}

__global__ __launch_bounds__(64, 3)
void ssim_v5_kernel(const float* __restrict__ imgA,
                    const float* __restrict__ imgB,
                    float* __restrict__ accum)
{
    constexpr float GW[11] = {
        0.00102838f, 0.00759880f, 0.03600077f, 0.10936070f, 0.21300554f,
        0.26601173f,
        0.21300554f, 0.10936070f, 0.03600077f, 0.00759880f, 0.00102838f
    };

    // ping-pong x 2 rows x 80 interleaved {a,b} pairs (160 floats) = 2560 B
    __shared__ __attribute__((aligned(16))) float sbuf[2][2][160];

    const int lane = threadIdx.x;
    const int C0 = blockIdx.x * 64;
    const int R0 = blockIdx.y * SROWS;
    const size_t pOff = (size_t)blockIdx.z * (size_t)(IMG * IMG);

    // staging: lanes 0..19 -> row pair member 0, lanes 20..39 -> member 1;
    // each staging lane loads+stores one 4-col quad of BOTH images.
    const int  srow = (lane >= 20) ? 1 : 0;
    const bool stg  = lane < 40;
    const int  q    = lane - 20 * srow;          // 0..19 for staging lanes
    const int  col0 = C0 - 8 + 4 * q;            // quad-aligned, never straddles
    const bool okc  = stg && (col0 >= 0) && (col0 <= IMG - 4);
    const float* gA = imgA + pOff + col0;
    const float* gB = imgB + pOff + col0;
    const int  ir0  = R0 - 5 + srow;

    float4 pa = make_float4(0.f, 0.f, 0.f, 0.f), pb = pa;   // prefetch regs

    auto fetch = [&](int r2) {      // r2 = first strip-row of the pair
        const int ir = ir0 + r2;    // absolute image row this lane loads
        pa = make_float4(0.f, 0.f, 0.f, 0.f);
        pb = make_float4(0.f, 0.f, 0.f, 0.f);
        if (okc && (unsigned)ir < (unsigned)IMG) {
            const size_t o = (size_t)ir * IMG;
            pa = *(const float4*)(gA + o);
            pb = *(const float4*)(gB + o);
        }
    };
    auto stage = [&](int par) {
        if (stg) {
            v4f w0 = {clamp01(pa.x), clamp01(pb.x), clamp01(pa.y), clamp01(pb.y)};
            v4f w1 = {clamp01(pa.z), clamp01(pb.z), clamp01(pa.w), clamp01(pb.w)};
            v4f* d = (v4f*)&sbuf[par][srow][8 * q];
            d[0] = w0;
            d[1] = w1;
        }
    };

    // 12-slot register ring of horizontal results: {h1,h2},{h11,h22},h12
    v2f rA[12], rB[12];
    float rC[12];
#pragma unroll
    for (int i = 0; i < 12; ++i) { rA[i] = (v2f)0; rB[i] = (v2f)0; rC[i] = 0.f; }

    float lsum = 0.f;

    auto hconv = [&](const v2f* w, int slot) {
        v2f hA = (v2f)0, hB = (v2f)0;
        float hC = 0.f;
#pragma unroll
        for (int j = 0; j < 11; ++j) {
            v2f wj = w[j];
            v2f g  = GW[j] * wj;            // {g*a, g*b}   pk_mul
            hA += g;                        // {h1, h2}     pk_add
            hB += g * wj;                   // {h11, h22}   pk_fma
            hC  = fmaf(g.x, wj.y, hC);      // h12
        }
        rA[slot] = hA; rB[slot] = hB; rC[slot] = hC;
    };
    auto vconv = [&](int base) {            // ring slots (base+i)%12, static
        v2f vA = (v2f)0, vB = (v2f)0;
        float vC = 0.f;
#pragma unroll
        for (int i = 0; i < 11; ++i) {
            const int sl = (base + i) % 12;
            const float gi = GW[i];
            vA += gi * rA[sl];
            vB += gi * rB[sl];
            vC  = fmaf(gi, rC[sl], vC);
        }
        lsum += ssim_px(vA, vB, vC);
    };

    // uu = t % 12 (compile-time under the unrolled chunk)
    auto body = [&](int t, int uu, bool dovert, bool dostage, bool dofetch) {
        const int par = uu & 1;
        const int s0  = (2 * uu) % 12;
        // 1. window reads (buffer staged during step t-1); pairs lane+3..lane+13
        v2f w0[11], w1[11];
        const v2f* p0 = (const v2f*)&sbuf[par][0][0] + (lane + 3);
        const v2f* p1 = (const v2f*)&sbuf[par][1][0] + (lane + 3);
#pragma unroll
        for (int j = 0; j < 11; ++j) { w0[j] = p0[j]; w1[j] = p1[j]; }
        // 2. stage rows 2t+2, 2t+3 (fetched during step t-1) into other buffer
        if (dostage) stage(par ^ 1);
        // 3. prefetch rows 2t+4, 2t+5
        if (dofetch) fetch(2 * t + 4);
        // 4. horizontal conv, ring push (rows 2t -> s0, 2t+1 -> s0+1)
        hconv(w0, s0);
        hconv(w1, s0 + 1);
        // 5. vertical + SSIM for output rows 2t-10, 2t-9
        if (dovert) {
            vconv((s0 + 2) % 12);
            vconv((s0 + 3) % 12);
        }
    };

    // prologue: rows 0,1 -> P -> sbuf[0]; rows 2,3 -> P
    fetch(0);
    stage(0);
    fetch(2);

    // 3 chunks of 12 steps (t = 0..35); dovert runtime but wave-uniform
#pragma unroll 1
    for (int c = 0; c < 3; ++c) {
        const int tb = 12 * c;
#pragma unroll
        for (int uu = 0; uu < 12; ++uu)
            body(tb + uu, uu, (tb + uu) >= 5, true, true);
    }
    // tail t = 36 (uu = 0, par = 0): emits output rows 62, 63
    body(36, 0, true, false, false);

    // wave64 reduce, one atomic per wave
#pragma unroll
    for (int off = 32; off >= 1; off >>= 1)
        lsum += __shfl_down(lsum, off, 64);
    if (lane == 0) atomicAdd(accum, lsum);
}

__global__ void ssim_finalize_kernel(const float* __restrict__ accum,
                                     float* __restrict__ out) {
    out[0] = 1.0f - accum[0] * (1.0f / NPIX);
}

extern "C" void kernel_launch(void* const* d_in, const int* in_sizes, int n_in,
                              void* d_out, int out_size, void* d_ws, size_t ws_size,
                              hipStream_t stream) {
    const float* img1 = (const float*)d_in[0];
    const float* img2 = (const float*)d_in[1];
    float* out = (float*)d_out;
    float* wsf = (float*)d_ws;

    hipMemsetAsync(wsf, 0, 64, stream);     // accumulator (ws re-poisoned per call)

    dim3 grid(IMG / 64, IMG / SROWS, 48);   // 8 x 8 x 48 = 3072 single-wave blocks
    ssim_v5_kernel<<<grid, 64, 0, stream>>>(img1, img2, wsf);
    ssim_finalize_kernel<<<1, 1, 0, stream>>>(wsf, out);
}

// Round 6
// 226.299 us; speedup vs baseline: 1.8971x; 1.8971x over previous
//
#include <hip/hip_runtime.h>

// SSIM loss v6 — R2's proven streaming shape + 2x wave count + true ping-pong.
// Grid 4 x 32 x 48 = 6144 blocks of 64 threads = 1 wave (no barriers).
// Wave strip: 128 cols x 16 output rows (26 input rows = 26 steps).
// Each lane owns 2 adjacent output cols (2L, 2L+1). Per step s:
//   1. read 12 interleaved {a,b} v2f window pairs from sbuf[s&1]
//      (staged during step s-1; one full step of write->read slack),
//   2. stage row s+1 (prefetched during s-1) into sbuf[(s+1)&1],
//   3. prefetch row s+2 into registers (2x float4, 36 staging lanes),
//   4. horizontal 11-tap conv x 2 cols (packed f32) -> 11-slot register ring
//      (slot = s mod 11, static under chunk-of-11 unroll),
//   5. vertical 11-tap conv from ring + SSIM for output row s-10 (2 px).
// One float atomicAdd per wave; finalize: 1 - sum/N.

typedef float v2f __attribute__((ext_vector_type(2)));
typedef float v4f __attribute__((ext_vector_type(4)));

#define IMG    512
#define SROWS  16
#define NSTEPS 26           // SROWS + 10
#define BUFW   288          // (128 + 16 halo) cols * 2 images, interleaved {a,b}
#define NPIX   (16.0f * 3.0f * 512.0f * 512.0f)

__device__ __forceinline__ float clamp01(float x) {
    // fmaxf(NaN,0) -> 0: nan_to_num + clip(0,1)
    return fminf(fmaxf(x, 0.0f), 1.0f);
}

__device__ __forceinline__ float ssim_px(v2f mu, v2f e, float e12) {
    const float C1 = 1.01e-4f;   // 0.01^2 + 1e-6
    const float C2 = 9.01e-4f;   // 0.03^2 + 1e-6
    v2f musq = mu * mu;
    float mu12 = mu.x * mu.y;
    v2f sig = e - musq;
    sig = __builtin_elementwise_max(sig, (v2f){1e-6f, 1e-6f});
    sig = __builtin_elementwise_min(sig, (v2f){1e6f, 1e6f});
    float s12 = e12 - mu12;
    float num = fmaf(2.f, mu12, C1) * fmaf(2.f, s12, C2);
    float den = (musq.x + musq.y + C1) * (sig.x + sig.y + C2);  // >= C1*C2 > 0
    return num * __builtin_amdgcn_rcpf(den);
}

__global__ __launch_bounds__(64, 2)
void ssim_v6_kernel(const float* __restrict__ imgA,
                    const float* __restrict__ imgB,
                    float* __restrict__ accum)
{
    constexpr float GW[11] = {
        0.00102838f, 0.00759880f, 0.03600077f, 0.10936070f, 0.21300554f,
        0.26601173f,
        0.21300554f, 0.10936070f, 0.03600077f, 0.00759880f, 0.00102838f
    };

    __shared__ __attribute__((aligned(16))) float sbuf[2][BUFW];   // 2304 B

    const int lane = threadIdx.x;
    const int C0 = blockIdx.x * 128;
    const int R0 = blockIdx.y * SROWS;
    const size_t pOff = (size_t)blockIdx.z * (size_t)(IMG * IMG);

    // staging: lanes 0..35 each own one 4-col quad of BOTH images.
    // quad q=lane covers cols C0-8+4q..+3 -> interleaved words 8q..8q+7.
    const bool stg  = lane < 36;
    const int  col0 = C0 - 8 + 4 * lane;            // quad-aligned, no straddle
    const bool okc  = stg && (col0 >= 0) && (col0 <= IMG - 4);
    const float* gA = imgA + pOff + col0;
    const float* gB = imgB + pOff + col0;

    float4 pa = make_float4(0.f, 0.f, 0.f, 0.f), pb = pa;   // prefetch regs

    auto fetch = [&](int s) {
        const int ir = R0 - 5 + s;
        pa = make_float4(0.f, 0.f, 0.f, 0.f);
        pb = make_float4(0.f, 0.f, 0.f, 0.f);
        if (okc && (unsigned)ir < (unsigned)IMG) {
            const size_t o = (size_t)ir * IMG;
            pa = *(const float4*)(gA + o);
            pb = *(const float4*)(gB + o);
        }
    };
    auto stage = [&](int par) {
        if (stg) {
            v4f w0 = {clamp01(pa.x), clamp01(pb.x), clamp01(pa.y), clamp01(pb.y)};
            v4f w1 = {clamp01(pa.z), clamp01(pb.z), clamp01(pa.w), clamp01(pb.w)};
            v4f* d = (v4f*)&sbuf[par][8 * lane];
            d[0] = w0;
            d[1] = w1;
        }
    };

    // 11-slot register ring x 2 cols: {h1,h2} pair, {h11,h22} pair, h12
    v2f rA[11][2], rB[11][2];
    float rC[11][2];
#pragma unroll
    for (int i = 0; i < 11; ++i) {
        rA[i][0] = (v2f)0; rA[i][1] = (v2f)0;
        rB[i][0] = (v2f)0; rB[i][1] = (v2f)0;
        rC[i][0] = 0.f;    rC[i][1] = 0.f;
    }

    float lsum = 0.f;

    auto body = [&](int s, int u, bool dovert) {
        const int par = s & 1;

        // 1. window: cols 2L-5 .. 2L+6 -> v2f pairs (2L+3)..(2L+14)
        v2f w[12];
        const v2f* wp = (const v2f*)&sbuf[par][0] + (2 * lane + 3);
#pragma unroll
        for (int j = 0; j < 12; ++j) w[j] = wp[j];

        // 2. stage row s+1 (fetched during step s-1) into the other buffer
        stage(par ^ 1);

        // 3. prefetch row s+2 (consumed by stage during step s+1)
        fetch(s + 2);

        // 4. horizontal conv: col0 uses w[j], col1 uses w[j+1]
        v2f hA0 = (v2f)0, hB0 = (v2f)0, hA1 = (v2f)0, hB1 = (v2f)0;
        float hC0 = 0.f, hC1 = 0.f;
#pragma unroll
        for (int j = 0; j < 11; ++j) {
            const float gj = GW[j];
            v2f w0 = w[j], w1 = w[j + 1];
            v2f g0 = gj * w0;                // {g*a, g*b}   pk_mul
            v2f g1 = gj * w1;
            hA0 += g0;  hA1 += g1;           // {h1, h2}     pk_add
            hB0 += g0 * w0;                  // {h11, h22}   pk_fma
            hB1 += g1 * w1;
            hC0 = fmaf(g0.x, w0.y, hC0);     // h12
            hC1 = fmaf(g1.x, w1.y, hC1);
        }
        rA[u][0] = hA0; rA[u][1] = hA1;
        rB[u][0] = hB0; rB[u][1] = hB1;
        rC[u][0] = hC0; rC[u][1] = hC1;

        // 5. vertical conv from ring + SSIM (output row R0+s-10, 2 px)
        if (dovert) {
            v2f vA0 = (v2f)0, vA1 = (v2f)0, vB0 = (v2f)0, vB1 = (v2f)0;
            float vC0 = 0.f, vC1 = 0.f;
#pragma unroll
            for (int i = 0; i < 11; ++i) {
                const int sl = (u + 1 + i) % 11;   // slot of row s-10+i (static)
                const float gi = GW[i];
                vA0 += gi * rA[sl][0]; vA1 += gi * rA[sl][1];
                vB0 += gi * rB[sl][0]; vB1 += gi * rB[sl][1];
                vC0 = fmaf(gi, rC[sl][0], vC0);
                vC1 = fmaf(gi, rC[sl][1], vC1);
            }
            lsum += ssim_px(vA0, vB0, vC0);
            lsum += ssim_px(vA1, vB1, vC1);
        }
    };

    // prologue: row 0 -> sbuf[0]; row 1 -> prefetch regs
    fetch(0);
    stage(0);
    fetch(1);

    // 2 chunks of 11 steps (s = 0..21), then static tail (s = 22..25)
#pragma unroll 1
    for (int c = 0; c < 2; ++c) {
        const int sb = 11 * c;
#pragma unroll
        for (int u = 0; u < 11; ++u)
            body(sb + u, u, (sb + u) >= 10);
    }
    body(22, 0, true);
    body(23, 1, true);
    body(24, 2, true);
    body(25, 3, true);

    // wave64 reduce, one atomic per wave
#pragma unroll
    for (int off = 32; off >= 1; off >>= 1)
        lsum += __shfl_down(lsum, off, 64);
    if (lane == 0) atomicAdd(accum, lsum);
}

__global__ void ssim_finalize_kernel(const float* __restrict__ accum,
                                     float* __restrict__ out) {
    out[0] = 1.0f - accum[0] * (1.0f / NPIX);
}

extern "C" void kernel_launch(void* const* d_in, const int* in_sizes, int n_in,
                              void* d_out, int out_size, void* d_ws, size_t ws_size,
                              hipStream_t stream) {
    const float* img1 = (const float*)d_in[0];
    const float* img2 = (const float*)d_in[1];
    float* out = (float*)d_out;
    float* wsf = (float*)d_ws;

    hipMemsetAsync(wsf, 0, 64, stream);     // accumulator (ws re-poisoned per call)

    dim3 grid(IMG / 128, IMG / SROWS, 48);  // 4 x 32 x 48 = 6144 single-wave blocks
    ssim_v6_kernel<<<grid, 64, 0, stream>>>(img1, img2, wsf);
    ssim_finalize_kernel<<<1, 1, 0, stream>>>(wsf, out);
}